// Round 3
// baseline (126.221 us; speedup 1.0000x reference)
//
#include <hip/hip_runtime.h>
#include <math.h>

#define DIM    128
#define DIM2   256
#define NSIGN  4
#define CCONST 0.618f
#define TB     4
#define NTHR   256

// Build W1T[j][k] = W1[k][j]  (W1 is [256][128])
//       W2T[k][i] = W2[i][k]  (W2 is [128][256])
__global__ void prep_transpose(const float* __restrict__ W1,
                               const float* __restrict__ W2,
                               float* __restrict__ W1T,
                               float* __restrict__ W2T) {
    int idx = blockIdx.x * blockDim.x + threadIdx.x;
    if (idx >= DIM * DIM2) return;
    int k = idx >> 7;            // W1 row (0..255)
    int j = idx & (DIM - 1);     // W1 col (0..127)
    W1T[j * DIM2 + k] = W1[idx];
    int i  = idx >> 8;           // W2 row (0..127)
    int kk = idx & (DIM2 - 1);   // W2 col (0..255)
    W2T[kk * DIM + i] = W2[idx];
}

__global__ __launch_bounds__(NTHR, 4)
void fused_connection(const float* __restrict__ input_,
                      const float* __restrict__ W1,
                      const float* __restrict__ b1,
                      const float* __restrict__ W2,
                      const float* __restrict__ b2,
                      const float* __restrict__ W1T,
                      const float* __restrict__ W2T,
                      float* __restrict__ out) {
    // Per-block LDS: 16 KB
    __shared__ __align__(16) float xv[TB][DIM2]; // x | v ; x-half becomes vc after stage 2
    __shared__ __align__(16) float am[TB][DIM2]; // a = relu(h)  (mask source)
    __shared__ __align__(16) float wb[TB][DIM2]; // w = v@W1^T; masked in stage 3
    __shared__ __align__(16) float ub[TB][DIM2]; // mu = mask * u

    const int t  = threadIdx.x;
    const int b0 = blockIdx.x * TB;

    // ---------- Phase 0: load x|v rows (TB*256 = 1024 floats, coalesced float4) ----------
    {
        const float4* src = (const float4*)(input_ + (size_t)b0 * DIM2);
        float4* dst = (float4*)(&xv[0][0]);
        dst[t] = src[t];
    }
    __syncthreads();

    // copy v -> out[:, :128]  (TB*128 = 512 floats = 256 float2)
    {
        int row = t >> 6;
        int c2  = (t & 63) * 2;
        float2 vv = *(const float2*)(&xv[row][DIM + c2]);
        *(float2*)(out + (size_t)(b0 + row) * DIM2 + c2) = vv;
    }

    // Mappings:
    //   N=256 stages (1,3): rg = t>>7 (2 groups x 2 rows), k0 = (t&127)*2 (2 cols)
    //   N=128 stages (2,4): rg2 = t>>6 (4 groups x 1 row), i0 = (t&63)*2 (2 cols)
    const int rg  = t >> 7;
    const int r0  = rg * 2;
    const int k0  = (t & 127) * 2;
    const int r2  = t >> 6;
    const int i0  = (t & 63) * 2;

    // ---------- Stage 1: h[b,k] = x.W1[k,:] + b1[k]; w[b,k] = v.W1[k,:] ----------
    // weights from W1T[j][k] -> lanes contiguous in k. 2 rows x 2 cols per thread.
    {
        float ha[2][2], wa[2][2];
        const float bv0 = b1[k0], bv1 = b1[k0 + 1];
        #pragma unroll
        for (int rr = 0; rr < 2; ++rr) {
            ha[rr][0] = bv0; ha[rr][1] = bv1;
            wa[rr][0] = 0.f; wa[rr][1] = 0.f;
        }
        #pragma unroll 4
        for (int j4 = 0; j4 < DIM; j4 += 4) {
            const float2 w0 = *(const float2*)(W1T + (j4 + 0) * DIM2 + k0);
            const float2 w1 = *(const float2*)(W1T + (j4 + 1) * DIM2 + k0);
            const float2 w2 = *(const float2*)(W1T + (j4 + 2) * DIM2 + k0);
            const float2 w3 = *(const float2*)(W1T + (j4 + 3) * DIM2 + k0);
            #pragma unroll
            for (int rr = 0; rr < 2; ++rr) {
                const float4 xr = *(const float4*)(&xv[r0 + rr][j4]);
                const float4 vr = *(const float4*)(&xv[r0 + rr][DIM + j4]);
                ha[rr][0] = fmaf(xr.x, w0.x, ha[rr][0]); ha[rr][1] = fmaf(xr.x, w0.y, ha[rr][1]);
                ha[rr][0] = fmaf(xr.y, w1.x, ha[rr][0]); ha[rr][1] = fmaf(xr.y, w1.y, ha[rr][1]);
                ha[rr][0] = fmaf(xr.z, w2.x, ha[rr][0]); ha[rr][1] = fmaf(xr.z, w2.y, ha[rr][1]);
                ha[rr][0] = fmaf(xr.w, w3.x, ha[rr][0]); ha[rr][1] = fmaf(xr.w, w3.y, ha[rr][1]);
                wa[rr][0] = fmaf(vr.x, w0.x, wa[rr][0]); wa[rr][1] = fmaf(vr.x, w0.y, wa[rr][1]);
                wa[rr][0] = fmaf(vr.y, w1.x, wa[rr][0]); wa[rr][1] = fmaf(vr.y, w1.y, wa[rr][1]);
                wa[rr][0] = fmaf(vr.z, w2.x, wa[rr][0]); wa[rr][1] = fmaf(vr.z, w2.y, wa[rr][1]);
                wa[rr][0] = fmaf(vr.w, w3.x, wa[rr][0]); wa[rr][1] = fmaf(vr.w, w3.y, wa[rr][1]);
            }
        }
        #pragma unroll
        for (int rr = 0; rr < 2; ++rr) {
            float2 av, wv;
            av.x = fmaxf(ha[rr][0], 0.f); av.y = fmaxf(ha[rr][1], 0.f);
            wv.x = wa[rr][0];             wv.y = wa[rr][1];
            *(float2*)(&am[r0 + rr][k0]) = av;
            *(float2*)(&wb[r0 + rr][k0]) = wv;
        }
    }
    __syncthreads();

    // ---------- Stage 2: z[b,i] = a.W2[i,:] + b2[i]; s kept in regs; vc -> xv x-half ----------
    // weights from W2T[k][i] -> lanes contiguous in i. 1 row x 2 cols per thread.
    float sreg[2];
    {
        float za0 = b2[i0], za1 = b2[i0 + 1];
        #pragma unroll 4
        for (int k4 = 0; k4 < DIM2; k4 += 4) {
            const float2 q0 = *(const float2*)(W2T + (k4 + 0) * DIM + i0);
            const float2 q1 = *(const float2*)(W2T + (k4 + 1) * DIM + i0);
            const float2 q2 = *(const float2*)(W2T + (k4 + 2) * DIM + i0);
            const float2 q3 = *(const float2*)(W2T + (k4 + 3) * DIM + i0);
            const float4 ar = *(const float4*)(&am[r2][k4]);
            za0 = fmaf(ar.x, q0.x, za0); za1 = fmaf(ar.x, q0.y, za1);
            za0 = fmaf(ar.y, q1.x, za0); za1 = fmaf(ar.y, q1.y, za1);
            za0 = fmaf(ar.z, q2.x, za0); za1 = fmaf(ar.z, q2.y, za1);
            za0 = fmaf(ar.w, q3.x, za0); za1 = fmaf(ar.w, q3.y, za1);
        }
        const float sg0 = (i0     < NSIGN) ? -1.f : 1.f;
        const float sg1 = (i0 + 1 < NSIGN) ? -1.f : 1.f;
        const float s0 = 1.f / (1.f + __expf(-za0));
        const float s1 = 1.f / (1.f + __expf(-za1));
        sreg[0] = s0; sreg[1] = s1;
        const float2 vv = *(const float2*)(&xv[r2][DIM + i0]);
        float2 vc;
        vc.x = vv.x * vv.x * sg0 * s0 * (1.f - s0);
        vc.y = vv.y * vv.y * sg1 * s1 * (1.f - s1);
        *(float2*)(&xv[r2][i0]) = vc;   // overwrite dead x-half
    }
    __syncthreads();

    // ---------- Stage 3: u[b,k] = vc.W2[:,k]; mu = m*u -> ub; mw = m*w -> wb ----------
    // weights from W2[i][k] (native row-major) -> lanes contiguous in k. 2 rows x 2 cols.
    {
        float ua[2][2] = {{0.f,0.f},{0.f,0.f}};
        #pragma unroll 4
        for (int i4 = 0; i4 < DIM; i4 += 4) {
            const float2 w0 = *(const float2*)(W2 + (i4 + 0) * DIM2 + k0);
            const float2 w1 = *(const float2*)(W2 + (i4 + 1) * DIM2 + k0);
            const float2 w2 = *(const float2*)(W2 + (i4 + 2) * DIM2 + k0);
            const float2 w3 = *(const float2*)(W2 + (i4 + 3) * DIM2 + k0);
            #pragma unroll
            for (int rr = 0; rr < 2; ++rr) {
                const float4 cr = *(const float4*)(&xv[r0 + rr][i4]);
                ua[rr][0] = fmaf(cr.x, w0.x, ua[rr][0]); ua[rr][1] = fmaf(cr.x, w0.y, ua[rr][1]);
                ua[rr][0] = fmaf(cr.y, w1.x, ua[rr][0]); ua[rr][1] = fmaf(cr.y, w1.y, ua[rr][1]);
                ua[rr][0] = fmaf(cr.z, w2.x, ua[rr][0]); ua[rr][1] = fmaf(cr.z, w2.y, ua[rr][1]);
                ua[rr][0] = fmaf(cr.w, w3.x, ua[rr][0]); ua[rr][1] = fmaf(cr.w, w3.y, ua[rr][1]);
            }
        }
        #pragma unroll
        for (int rr = 0; rr < 2; ++rr) {
            const int row = r0 + rr;
            const float2 amv = *(const float2*)(&am[row][k0]);
            const float2 wv  = *(const float2*)(&wb[row][k0]);
            float2 uo, wo;
            uo.x = (amv.x > 0.f) ? ua[rr][0] : 0.f;  wo.x = (amv.x > 0.f) ? wv.x : 0.f;
            uo.y = (amv.y > 0.f) ? ua[rr][1] : 0.f;  wo.y = (amv.y > 0.f) ? wv.y : 0.f;
            *(float2*)(&ub[row][k0]) = uo;
            *(float2*)(&wb[row][k0]) = wo;
        }
    }
    __syncthreads();

    // ---------- Stage 4: t1[b,j] = mu.W1[:,j]; t2[b,j] = mw.W2T[:,j]; dv ----------
    // W1[k][j] native (j contiguous), W2T[k][j] (j contiguous). 1 row x 2 cols.
    {
        float t10 = 0.f, t11 = 0.f, t20 = 0.f, t21 = 0.f;
        #pragma unroll 4
        for (int k4 = 0; k4 < DIM2; k4 += 4) {
            const float2 a0 = *(const float2*)(W1  + (k4 + 0) * DIM + i0);
            const float2 a1 = *(const float2*)(W1  + (k4 + 1) * DIM + i0);
            const float2 a2 = *(const float2*)(W1  + (k4 + 2) * DIM + i0);
            const float2 a3 = *(const float2*)(W1  + (k4 + 3) * DIM + i0);
            const float2 c0 = *(const float2*)(W2T + (k4 + 0) * DIM + i0);
            const float2 c1 = *(const float2*)(W2T + (k4 + 1) * DIM + i0);
            const float2 c2 = *(const float2*)(W2T + (k4 + 2) * DIM + i0);
            const float2 c3 = *(const float2*)(W2T + (k4 + 3) * DIM + i0);
            const float4 ur = *(const float4*)(&ub[r2][k4]);
            const float4 wr = *(const float4*)(&wb[r2][k4]);
            t10 = fmaf(ur.x, a0.x, t10); t11 = fmaf(ur.x, a0.y, t11);
            t10 = fmaf(ur.y, a1.x, t10); t11 = fmaf(ur.y, a1.y, t11);
            t10 = fmaf(ur.z, a2.x, t10); t11 = fmaf(ur.z, a2.y, t11);
            t10 = fmaf(ur.w, a3.x, t10); t11 = fmaf(ur.w, a3.y, t11);
            t20 = fmaf(wr.x, c0.x, t20); t21 = fmaf(wr.x, c0.y, t21);
            t20 = fmaf(wr.y, c1.x, t20); t21 = fmaf(wr.y, c1.y, t21);
            t20 = fmaf(wr.z, c2.x, t20); t21 = fmaf(wr.z, c2.y, t21);
            t20 = fmaf(wr.w, c3.x, t20); t21 = fmaf(wr.w, c3.y, t21);
        }
        const float sg0 = (i0     < NSIGN) ? -1.f : 1.f;
        const float sg1 = (i0 + 1 < NSIGN) ? -1.f : 1.f;
        const float s0 = sreg[0], s1 = sreg[1];
        const float cv0 = sg0 * s0 * (1.f - s0);
        const float cv1 = sg1 * s1 * (1.f - s1);
        const float gi0 = 1.f / (sg0 * (s0 + CCONST));
        const float gi1 = 1.f / (sg1 * (s1 + CCONST));
        const float2 vv = *(const float2*)(&xv[r2][DIM + i0]);
        float2 dvp;
        dvp.x = fmaf(-gi0, t10, 2.f * vv.x * gi0 * cv0 * t20);
        dvp.y = fmaf(-gi1, t11, 2.f * vv.y * gi1 * cv1 * t21);
        *(float2*)(out + (size_t)(b0 + r2) * DIM2 + DIM + i0) = dvp;
    }
}

extern "C" void kernel_launch(void* const* d_in, const int* in_sizes, int n_in,
                              void* d_out, int out_size, void* d_ws, size_t ws_size,
                              hipStream_t stream) {
    // inputs: t, input_, W1, b1, W2, b2
    const float* input_ = (const float*)d_in[1];
    const float* W1 = (const float*)d_in[2];
    const float* b1 = (const float*)d_in[3];
    const float* W2 = (const float*)d_in[4];
    const float* b2 = (const float*)d_in[5];
    float* out = (float*)d_out;

    float* W1T = (float*)d_ws;            // 128*256 floats
    float* W2T = W1T + DIM * DIM2;        // 256*128 floats

    const int batch = in_sizes[1] / DIM2;

    prep_transpose<<<(DIM * DIM2 + 255) / 256, 256, 0, stream>>>(W1, W2, W1T, W2T);
    fused_connection<<<batch / TB, NTHR, 0, stream>>>(input_, W1, b1, W2, b2, W1T, W2T, out);
}

// Round 4
// 26.602 us; speedup vs baseline: 4.7448x; 4.7448x over previous
//
#include <hip/hip_runtime.h>
#include <math.h>

#define DIM    128
#define DIM2   256
#define NSIGN  4
#define CCONST 0.618f
#define MB     16
#define NTHR   512

typedef short bf16x8 __attribute__((ext_vector_type(8)));
typedef float f32x4  __attribute__((ext_vector_type(4)));

#define MFMA(a,b,c) __builtin_amdgcn_mfma_f32_16x16x32_bf16((a),(b),(c),0,0,0)

union BU { uint4 q; bf16x8 b; };

__device__ __forceinline__ unsigned short f2bf(float f) {
    unsigned u = __float_as_uint(f);
    u += 0x7fffu + ((u >> 16) & 1u);          // round-to-nearest-even
    return (unsigned short)(u >> 16);
}
__device__ __forceinline__ float bf2f(unsigned short h) {
    return __uint_as_float(((unsigned)h) << 16);
}

__device__ __forceinline__ void cvt8(const float* p, bf16x8& h8, bf16x8& l8) {
    union { unsigned short u[8]; bf16x8 v; } H, L;
    #pragma unroll
    for (int e = 0; e < 8; ++e) {
        float f = p[e];
        unsigned short hb = f2bf(f);
        H.u[e] = hb;
        L.u[e] = f2bf(f - bf2f(hb));
    }
    h8 = H.v; l8 = L.v;
}

__device__ __forceinline__ bf16x8 frag16(const unsigned short* p) {
    BU u; u.q = *(const uint4*)p; return u.b;
}

// ---------------- prep: pack 4 weight panels into MFMA fragment order ----------------
// pack m: [nt][kt][lane][e] with value B[kt*32 + 8*(lane>>4) + e][nt*16 + (lane&15)]
//   m=0: B = W1T (128x256)  B[r][c] = W1[c*128 + r]
//   m=1: B = W2T (256x128)  B[r][c] = W2[c*256 + r]
//   m=2: B = W2  (128x256)  B[r][c] = W2[r*256 + c]
//   m=3: B = W1  (256x128)  B[r][c] = W1[r*128 + c]
// each pack: hi plane 32768 ushort, lo plane 32768 ushort (pack stride 65536)
__global__ void prep_pack(const float* __restrict__ W1, const float* __restrict__ W2,
                          unsigned short* __restrict__ pk) {
    int tid  = blockIdx.x * 256 + threadIdx.x;   // 16384 threads
    int m    = tid >> 12;
    int f    = tid & 4095;
    int lane = f & 63;
    int tkt  = f >> 6;                           // 0..63 == nt*KT + kt
    int r0   = ((tkt & ((m == 0 || m == 2) ? 3 : 7)) * 32) + ((lane >> 4) << 3);
    // column: nt*16 + (lane&15); nt = tkt / KT
    int nt   = tkt / ((m == 0 || m == 2) ? 4 : 8);
    int c    = nt * 16 + (lane & 15);

    union { uint4 q; unsigned short u[8]; } H, L;
    #pragma unroll
    for (int e = 0; e < 8; ++e) {
        int r = r0 + e;
        float v;
        if      (m == 0) v = W1[c * DIM  + r];
        else if (m == 1) v = W2[c * DIM2 + r];
        else if (m == 2) v = W2[r * DIM2 + c];
        else             v = W1[r * DIM  + c];
        unsigned short hb = f2bf(v);
        H.u[e] = hb;
        L.u[e] = f2bf(v - bf2f(hb));
    }
    size_t base = (size_t)m * 65536 + (size_t)(tkt * 64 + lane) * 8;
    *(uint4*)(pk + base)         = H.q;
    *(uint4*)(pk + base + 32768) = L.q;
}

// ---------------- fused main kernel ----------------
__global__ __launch_bounds__(NTHR, 1)
void fused_connection(const float* __restrict__ input_,
                      const float* __restrict__ W1,
                      const float* __restrict__ b1,
                      const float* __restrict__ W2,
                      const float* __restrict__ b2,
                      const unsigned short* __restrict__ pk,
                      float* __restrict__ out) {
    __shared__ __align__(16) float          xv [MB][260];   // x | v  fp32
    __shared__ __align__(16) unsigned short aH [MB][272];   // a  hi (bf16 bits)
    __shared__ __align__(16) unsigned short aL [MB][272];   // a  lo
    __shared__ __align__(16) unsigned short mwH[MB][272];   // mw hi ; reused as mu hi
    __shared__ __align__(16) unsigned short mwL[MB][272];   // mw lo ; reused as mu lo
    __shared__ __align__(16) unsigned short vcH[MB][144];   // vc hi
    __shared__ __align__(16) unsigned short vcL[MB][144];   // vc lo

    const int t    = threadIdx.x;
    const int lane = t & 63;
    const int w    = t >> 6;             // wave id 0..7
    const int b0   = blockIdx.x * MB;
    const int arow = lane & 15;          // A-frag row / C-frag col component
    const int kg   = (lane >> 4) << 3;   // k-offset of this lane group
    const int rbase = (lane >> 4) << 2;  // C/D row base (verified m89 layout)

    // ---- phase 0: stage x|v to LDS (coalesced), copy v -> out[:, :128] ----
    {
        int prow = t >> 5, pc = (t & 31) * 8;
        const float4* src = (const float4*)(input_ + (size_t)(b0 + prow) * DIM2 + pc);
        *(float4*)&xv[prow][pc]     = src[0];
        *(float4*)&xv[prow][pc + 4] = src[1];
    }
    __syncthreads();
    {
        int vrow = t >> 5, vc4 = (t & 31) * 4;
        *(float4*)(out + (size_t)(b0 + vrow) * DIM2 + vc4) = *(const float4*)&xv[vrow][DIM + vc4];
    }

    // ---- Pass 1: B=W1T -> h = x.W1^T + b1, w = v.W1^T ; write a, mw (masked w) ----
    {
        bf16x8 xH[4], xL[4], vH[4], vL[4];
        #pragma unroll
        for (int kt = 0; kt < 4; ++kt) {
            int k0 = kt * 32 + kg;
            cvt8(&xv[arow][k0],       xH[kt], xL[kt]);
            cvt8(&xv[arow][DIM + k0], vH[kt], vL[kt]);
        }
        #pragma unroll
        for (int nt2 = 0; nt2 < 2; ++nt2) {
            int nt = w * 2 + nt2;
            f32x4 ha = {0.f, 0.f, 0.f, 0.f};
            f32x4 wa = {0.f, 0.f, 0.f, 0.f};
            #pragma unroll
            for (int kt = 0; kt < 4; ++kt) {
                const unsigned short* bp = pk + (size_t)((nt * 4 + kt) * 64 + lane) * 8;
                bf16x8 bh = frag16(bp);
                bf16x8 bl = frag16(bp + 32768);
                ha = MFMA(xH[kt], bh, ha);
                ha = MFMA(xH[kt], bl, ha);
                ha = MFMA(xL[kt], bh, ha);
                wa = MFMA(vH[kt], bh, wa);
                wa = MFMA(vH[kt], bl, wa);
                wa = MFMA(vL[kt], bh, wa);
            }
            int col  = nt * 16 + arow;
            float bias = b1[col];
            #pragma unroll
            for (int reg = 0; reg < 4; ++reg) {
                int row = rbase + reg;
                float hv = ha[reg] + bias;
                if (fabsf(hv) < 1e-3f) {
                    // exact fp32 recompute to make the mask decision reliable
                    float acc2 = bias;
                    const float* w1r = W1 + (size_t)col * DIM;
                    for (int j = 0; j < DIM; ++j)
                        acc2 = fmaf(xv[row][j], w1r[j], acc2);
                    hv = acc2;
                }
                bool  mk = hv > 0.f;
                float av = mk ? hv : 0.f;
                unsigned short ah = f2bf(av);
                aH[row][col] = ah;
                aL[row][col] = f2bf(av - bf2f(ah));
                float mwv = mk ? wa[reg] : 0.f;
                unsigned short mh = f2bf(mwv);
                mwH[row][col] = mh;
                mwL[row][col] = f2bf(mwv - bf2f(mh));
            }
        }
    }
    __syncthreads();

    // ---- Pass 2: B=W2T -> z = a.W2^T + b2 (-> s), t2 = mw.W2^T ; write vc ----
    float sreg[4];
    f32x4 t2a = {0.f, 0.f, 0.f, 0.f};
    {
        const unsigned short* p1 = pk + 65536;
        f32x4 za = {0.f, 0.f, 0.f, 0.f};
        #pragma unroll
        for (int kt = 0; kt < 8; ++kt) {
            int k0 = kt * 32 + kg;
            bf16x8 af = frag16(&aH[arow][k0]);
            bf16x8 al = frag16(&aL[arow][k0]);
            bf16x8 mf = frag16(&mwH[arow][k0]);
            bf16x8 ml = frag16(&mwL[arow][k0]);
            const unsigned short* bp = p1 + (size_t)((w * 8 + kt) * 64 + lane) * 8;
            bf16x8 bh = frag16(bp);
            bf16x8 bl = frag16(bp + 32768);
            za  = MFMA(af, bh, za);  za  = MFMA(af, bl, za);  za  = MFMA(al, bh, za);
            t2a = MFMA(mf, bh, t2a); t2a = MFMA(mf, bl, t2a); t2a = MFMA(ml, bh, t2a);
        }
        int   ci   = w * 16 + arow;            // i in [0,128)
        float sg_i = (ci < NSIGN) ? -1.f : 1.f;
        float b2v  = b2[ci];
        #pragma unroll
        for (int reg = 0; reg < 4; ++reg) {
            int row = rbase + reg;
            float z = za[reg] + b2v;
            float s = 1.f / (1.f + __expf(-z));
            sreg[reg] = s;
            float vvl = xv[row][DIM + ci];
            float vc  = vvl * vvl * sg_i * s * (1.f - s);
            unsigned short vh = f2bf(vc);
            vcH[row][ci] = vh;
            vcL[row][ci] = f2bf(vc - bf2f(vh));
        }
    }
    __syncthreads();

    // ---- Pass 3: B=W2 -> u = vc.W2 ; write mu = mask*u into mw buffers ----
    {
        const unsigned short* p2 = pk + 2 * 65536;
        bf16x8 cH[4], cL[4];
        #pragma unroll
        for (int kt = 0; kt < 4; ++kt) {
            int k0 = kt * 32 + kg;
            cH[kt] = frag16(&vcH[arow][k0]);
            cL[kt] = frag16(&vcL[arow][k0]);
        }
        #pragma unroll
        for (int nt2 = 0; nt2 < 2; ++nt2) {
            int nt = w * 2 + nt2;
            f32x4 ua = {0.f, 0.f, 0.f, 0.f};
            #pragma unroll
            for (int kt = 0; kt < 4; ++kt) {
                const unsigned short* bp = p2 + (size_t)((nt * 4 + kt) * 64 + lane) * 8;
                bf16x8 bh = frag16(bp);
                bf16x8 bl = frag16(bp + 32768);
                ua = MFMA(cH[kt], bh, ua);
                ua = MFMA(cH[kt], bl, ua);
                ua = MFMA(cL[kt], bh, ua);
            }
            int ck = nt * 16 + arow;           // k in [0,256)
            #pragma unroll
            for (int reg = 0; reg < 4; ++reg) {
                int row = rbase + reg;
                bool mk = aH[row][ck] != 0;    // a>0 <=> mask (a>=0 stored)
                float muv = mk ? ua[reg] : 0.f;
                unsigned short mh = f2bf(muv);
                mwH[row][ck] = mh;
                mwL[row][ck] = f2bf(muv - bf2f(mh));
            }
        }
    }
    __syncthreads();

    // ---- Pass 4: B=W1 -> t1 = mu.W1 ; epilogue dv ----
    {
        const unsigned short* p3 = pk + 3 * 65536;
        f32x4 t1a = {0.f, 0.f, 0.f, 0.f};
        #pragma unroll
        for (int kt = 0; kt < 8; ++kt) {
            int k0 = kt * 32 + kg;
            bf16x8 mf = frag16(&mwH[arow][k0]);
            bf16x8 ml = frag16(&mwL[arow][k0]);
            const unsigned short* bp = p3 + (size_t)((w * 8 + kt) * 64 + lane) * 8;
            bf16x8 bh = frag16(bp);
            bf16x8 bl = frag16(bp + 32768);
            t1a = MFMA(mf, bh, t1a);
            t1a = MFMA(mf, bl, t1a);
            t1a = MFMA(ml, bh, t1a);
        }
        int   cj   = w * 16 + arow;            // same col as pass 2 -> sreg/t2a align
        float sg_j = (cj < NSIGN) ? -1.f : 1.f;
        #pragma unroll
        for (int reg = 0; reg < 4; ++reg) {
            int row = rbase + reg;
            float s  = sreg[reg];
            float cv = sg_j * s * (1.f - s);
            float gi = 1.f / (sg_j * (s + CCONST));
            float vvl = xv[row][DIM + cj];
            float dv = fmaf(-gi, t1a[reg], 2.f * vvl * gi * cv * t2a[reg]);
            out[(size_t)(b0 + row) * DIM2 + DIM + cj] = dv;
        }
    }
}

extern "C" void kernel_launch(void* const* d_in, const int* in_sizes, int n_in,
                              void* d_out, int out_size, void* d_ws, size_t ws_size,
                              hipStream_t stream) {
    // inputs: t, input_, W1, b1, W2, b2
    const float* input_ = (const float*)d_in[1];
    const float* W1 = (const float*)d_in[2];
    const float* b1 = (const float*)d_in[3];
    const float* W2 = (const float*)d_in[4];
    const float* b2 = (const float*)d_in[5];
    float* out = (float*)d_out;
    unsigned short* pk = (unsigned short*)d_ws;   // 4 packs x 128 KB = 512 KB

    const int batch = in_sizes[1] / DIM2;

    prep_pack<<<64, 256, 0, stream>>>(W1, W2, pk);
    fused_connection<<<batch / MB, NTHR, 0, stream>>>(input_, W1, b1, W2, b2, pk, out);
}

// Round 5
// 18.774 us; speedup vs baseline: 6.7232x; 1.4170x over previous
//
#include <hip/hip_runtime.h>
#include <math.h>

#define DIM    128
#define DIM2   256
#define NSIGN  4
#define CCONST 0.618f
#define MB     16
#define NTHR   512

typedef short bf16x8 __attribute__((ext_vector_type(8)));
typedef float f32x4  __attribute__((ext_vector_type(4)));

#define MFMA(a,b,c) __builtin_amdgcn_mfma_f32_16x16x32_bf16((a),(b),(c),0,0,0)

union BU { uint4 q; bf16x8 b; };

__device__ __forceinline__ unsigned short f2bf(float f) {
    unsigned u = __float_as_uint(f);
    u += 0x7fffu + ((u >> 16) & 1u);          // round-to-nearest-even
    return (unsigned short)(u >> 16);
}
__device__ __forceinline__ float bf2f(unsigned short h) {
    return __uint_as_float(((unsigned)h) << 16);
}

__device__ __forceinline__ void cvt8sp(const float* p, bf16x8& h8, bf16x8& l8) {
    union { unsigned short u[8]; bf16x8 v; } H, L;
    #pragma unroll
    for (int e = 0; e < 8; ++e) {
        float f = p[e];
        unsigned short hb = f2bf(f);
        H.u[e] = hb;
        L.u[e] = f2bf(f - bf2f(hb));
    }
    h8 = H.v; l8 = L.v;
}

__device__ __forceinline__ bf16x8 cvt8hi(const float* p) {
    union { unsigned short u[8]; bf16x8 v; } H;
    #pragma unroll
    for (int e = 0; e < 8; ++e) H.u[e] = f2bf(p[e]);
    return H.v;
}

__device__ __forceinline__ bf16x8 frag16(const unsigned short* p) {
    BU u; u.q = *(const uint4*)p; return u.b;
}

// ---------------- prep: pack 4 weight panels into MFMA fragment order ----------------
// pack m: [nt][kt][lane][e] with value B[kt*32 + 8*(lane>>4) + e][nt*16 + (lane&15)]
//   m=0: B = W1T (128x256)  B[r][c] = W1[c*128 + r]   (hi + lo planes)
//   m=1: B = W2T (256x128)  B[r][c] = W2[c*256 + r]   (hi only)
//   m=2: B = W2  (128x256)  B[r][c] = W2[r*256 + c]   (hi only)
//   m=3: B = W1  (256x128)  B[r][c] = W1[r*128 + c]   (hi only)
// pack stride 65536 ushort (hi plane 32768, lo plane 32768)
__global__ void prep_pack(const float* __restrict__ W1, const float* __restrict__ W2,
                          unsigned short* __restrict__ pk) {
    int tid  = blockIdx.x * 256 + threadIdx.x;   // 16384 threads
    int m    = tid >> 12;
    int f    = tid & 4095;
    int lane = f & 63;
    int tkt  = f >> 6;                           // nt*KT + kt
    int r0   = ((tkt & ((m == 0 || m == 2) ? 3 : 7)) * 32) + ((lane >> 4) << 3);
    int nt   = tkt / ((m == 0 || m == 2) ? 4 : 8);
    int c    = nt * 16 + (lane & 15);

    union { uint4 q; unsigned short u[8]; } H, L;
    #pragma unroll
    for (int e = 0; e < 8; ++e) {
        int r = r0 + e;
        float v;
        if      (m == 0) v = W1[c * DIM  + r];
        else if (m == 1) v = W2[c * DIM2 + r];
        else if (m == 2) v = W2[r * DIM2 + c];
        else             v = W1[r * DIM  + c];
        unsigned short hb = f2bf(v);
        H.u[e] = hb;
        L.u[e] = f2bf(v - bf2f(hb));
    }
    size_t base = (size_t)m * 65536 + (size_t)(tkt * 64 + lane) * 8;
    *(uint4*)(pk + base) = H.q;
    if (m == 0) *(uint4*)(pk + base + 32768) = L.q;
}

// ---------------- fused main kernel ----------------
__global__ __launch_bounds__(NTHR, 1)
void fused_connection(const float* __restrict__ input_,
                      const float* __restrict__ b1,
                      const float* __restrict__ b2,
                      const unsigned short* __restrict__ pk,
                      float* __restrict__ out) {
    __shared__ __align__(16) float          xv [MB][260];   // x | v  fp32 (stride 1040B: 2-way)
    __shared__ __align__(16) unsigned short aH [MB][264];   // a  bf16-hi  (stride 528B: 2-way)
    __shared__ __align__(16) unsigned short mwH[MB][264];   // mw hi ; reused as mu hi
    __shared__ __align__(16) unsigned short vcH[MB][136];   // vc hi       (stride 272B: 2-way)

    const int t    = threadIdx.x;
    const int lane = t & 63;
    const int w    = t >> 6;             // wave id 0..7
    const int b0   = blockIdx.x * MB;
    const int arow = lane & 15;          // A-frag row / C-frag col component
    const int kg   = (lane >> 4) << 3;   // k-offset of this lane group
    const int rbase = (lane >> 4) << 2;  // C/D row base (verified m89 layout)

    // ---- phase 0: stage x|v to LDS (coalesced), copy v -> out[:, :128] ----
    {
        int prow = t >> 5, pc = (t & 31) * 8;
        const float4* src = (const float4*)(input_ + (size_t)(b0 + prow) * DIM2 + pc);
        *(float4*)&xv[prow][pc]     = src[0];
        *(float4*)&xv[prow][pc + 4] = src[1];
    }
    __syncthreads();
    {
        int vrow = t >> 5, vc4 = (t & 31) * 4;
        *(float4*)(out + (size_t)(b0 + vrow) * DIM2 + vc4) = *(const float4*)&xv[vrow][DIM + vc4];
    }

    // ---- Pass 1: B=W1T -> h = x.W1^T + b1 (full split), w = v.W1^T (hi) ----
    {
        bf16x8 xH[4], xL[4], vH[4];
        #pragma unroll
        for (int kt = 0; kt < 4; ++kt) {
            int k0 = kt * 32 + kg;
            cvt8sp(&xv[arow][k0], xH[kt], xL[kt]);
            vH[kt] = cvt8hi(&xv[arow][DIM + k0]);
        }
        #pragma unroll
        for (int nt2 = 0; nt2 < 2; ++nt2) {
            int nt = w * 2 + nt2;
            f32x4 ha = {0.f, 0.f, 0.f, 0.f};
            f32x4 wa = {0.f, 0.f, 0.f, 0.f};
            #pragma unroll
            for (int kt = 0; kt < 4; ++kt) {
                const unsigned short* bp = pk + (size_t)((nt * 4 + kt) * 64 + lane) * 8;
                bf16x8 bh = frag16(bp);
                bf16x8 bl = frag16(bp + 32768);
                ha = MFMA(xH[kt], bh, ha);
                ha = MFMA(xH[kt], bl, ha);
                ha = MFMA(xL[kt], bh, ha);
                ha = MFMA(xL[kt], bl, ha);
                wa = MFMA(vH[kt], bh, wa);
            }
            int col  = nt * 16 + arow;
            float bias = b1[col];
            #pragma unroll
            for (int reg = 0; reg < 4; ++reg) {
                int row = rbase + reg;
                float hv = ha[reg] + bias;
                bool  mk = hv > 0.f;
                aH[row][col]  = f2bf(mk ? hv : 0.f);
                mwH[row][col] = f2bf(mk ? wa[reg] : 0.f);
            }
        }
    }
    __syncthreads();

    // ---- Pass 2: B=W2T(hi) -> z = a.W2^T + b2 (-> s), t2 = mw.W2^T ; write vc ----
    float sreg[4];
    f32x4 t2a = {0.f, 0.f, 0.f, 0.f};
    {
        const unsigned short* p1 = pk + 65536;
        f32x4 za = {0.f, 0.f, 0.f, 0.f};
        #pragma unroll
        for (int kt = 0; kt < 8; ++kt) {
            int k0 = kt * 32 + kg;
            bf16x8 af = frag16(&aH[arow][k0]);
            bf16x8 mf = frag16(&mwH[arow][k0]);
            bf16x8 bh = frag16(p1 + (size_t)((w * 8 + kt) * 64 + lane) * 8);
            za  = MFMA(af, bh, za);
            t2a = MFMA(mf, bh, t2a);
        }
        int   ci   = w * 16 + arow;            // i in [0,128)
        float sg_i = (ci < NSIGN) ? -1.f : 1.f;
        float b2v  = b2[ci];
        #pragma unroll
        for (int reg = 0; reg < 4; ++reg) {
            int row = rbase + reg;
            float z = za[reg] + b2v;
            float s = 1.f / (1.f + __expf(-z));
            sreg[reg] = s;
            float vvl = xv[row][DIM + ci];
            vcH[row][ci] = f2bf(vvl * vvl * sg_i * s * (1.f - s));
        }
    }
    __syncthreads();

    // ---- Pass 3: B=W2(hi) -> u = vc.W2 ; write mu = mask*u into mwH ----
    {
        const unsigned short* p2 = pk + 2 * 65536;
        bf16x8 cH[4];
        #pragma unroll
        for (int kt = 0; kt < 4; ++kt)
            cH[kt] = frag16(&vcH[arow][kt * 32 + kg]);
        #pragma unroll
        for (int nt2 = 0; nt2 < 2; ++nt2) {
            int nt = w * 2 + nt2;
            f32x4 ua = {0.f, 0.f, 0.f, 0.f};
            #pragma unroll
            for (int kt = 0; kt < 4; ++kt) {
                bf16x8 bh = frag16(p2 + (size_t)((nt * 4 + kt) * 64 + lane) * 8);
                ua = MFMA(cH[kt], bh, ua);
            }
            int ck = nt * 16 + arow;           // k in [0,256)
            #pragma unroll
            for (int reg = 0; reg < 4; ++reg) {
                int row = rbase + reg;
                bool mk = aH[row][ck] != 0;    // a>0 <=> stored bf16 nonzero
                mwH[row][ck] = f2bf(mk ? ua[reg] : 0.f);
            }
        }
    }
    __syncthreads();

    // ---- Pass 4: B=W1(hi) -> t1 = mu.W1 ; epilogue dv ----
    {
        const unsigned short* p3 = pk + 3 * 65536;
        f32x4 t1a = {0.f, 0.f, 0.f, 0.f};
        #pragma unroll
        for (int kt = 0; kt < 8; ++kt) {
            bf16x8 mf = frag16(&mwH[arow][kt * 32 + kg]);
            bf16x8 bh = frag16(p3 + (size_t)((w * 8 + kt) * 64 + lane) * 8);
            t1a = MFMA(mf, bh, t1a);
        }
        int   cj   = w * 16 + arow;            // same col as pass 2 -> sreg/t2a align
        float sg_j = (cj < NSIGN) ? -1.f : 1.f;
        #pragma unroll
        for (int reg = 0; reg < 4; ++reg) {
            int row = rbase + reg;
            float s  = sreg[reg];
            float cv = sg_j * s * (1.f - s);
            float gi = 1.f / (sg_j * (s + CCONST));
            float vvl = xv[row][DIM + cj];
            float dv = fmaf(-gi, t1a[reg], 2.f * vvl * gi * cv * t2a[reg]);
            out[(size_t)(b0 + row) * DIM2 + DIM + cj] = dv;
        }
    }
}

extern "C" void kernel_launch(void* const* d_in, const int* in_sizes, int n_in,
                              void* d_out, int out_size, void* d_ws, size_t ws_size,
                              hipStream_t stream) {
    // inputs: t, input_, W1, b1, W2, b2
    const float* input_ = (const float*)d_in[1];
    const float* W1 = (const float*)d_in[2];
    const float* b1 = (const float*)d_in[3];
    const float* W2 = (const float*)d_in[4];
    const float* b2 = (const float*)d_in[5];
    float* out = (float*)d_out;
    unsigned short* pk = (unsigned short*)d_ws;   // 4 packs x 128 KB = 512 KB

    const int batch = in_sizes[1] / DIM2;

    prep_pack<<<64, 256, 0, stream>>>(W1, W2, pk);
    fused_connection<<<batch / MB, NTHR, 0, stream>>>(input_, b1, b2, pk, out);
}

// Round 6
// 16.712 us; speedup vs baseline: 7.5526x; 1.1234x over previous
//
#include <hip/hip_runtime.h>
#include <math.h>

#define DIM    128
#define DIM2   256
#define NSIGN  4
#define CCONST 0.618f
#define MB     16
#define NTHR   512

typedef short bf16x8 __attribute__((ext_vector_type(8)));
typedef float f32x4  __attribute__((ext_vector_type(4)));

#define MFMA(a,b,c) __builtin_amdgcn_mfma_f32_16x16x32_bf16((a),(b),(c),0,0,0)

union BU { uint4 q; bf16x8 b; };

__device__ __forceinline__ unsigned short f2bf(float f) {
    unsigned u = __float_as_uint(f);
    u += 0x7fffu + ((u >> 16) & 1u);          // round-to-nearest-even
    return (unsigned short)(u >> 16);
}
__device__ __forceinline__ float bf2f(unsigned short h) {
    return __uint_as_float(((unsigned)h) << 16);
}
__device__ __forceinline__ bf16x8 frag16(const unsigned short* p) {
    BU u; u.q = *(const uint4*)p; return u.b;
}

// ---------------- prep: pack 4 weight panels into MFMA fragment order ----------------
// pack m: [nt][kt][lane][e] with value B[kt*32 + 8*(lane>>4) + e][nt*16 + (lane&15)]
//   m=0: B = W1T (128x256)  B[r][c] = W1[c*128 + r]   (hi + lo planes)
//   m=1: B = W2T (256x128)  B[r][c] = W2[c*256 + r]   (hi only)
//   m=2: B = W2  (128x256)  B[r][c] = W2[r*256 + c]   (hi only)
//   m=3: B = W1  (256x128)  B[r][c] = W1[r*128 + c]   (hi only)
// pack stride 65536 ushort (hi plane 32768, lo plane 32768)
__global__ void prep_pack(const float* __restrict__ W1, const float* __restrict__ W2,
                          unsigned short* __restrict__ pk) {
    int tid  = blockIdx.x * 256 + threadIdx.x;   // 16384 threads
    int m    = tid >> 12;
    int f    = tid & 4095;
    int lane = f & 63;
    int tkt  = f >> 6;                           // nt*KT + kt
    int r0   = ((tkt & ((m == 0 || m == 2) ? 3 : 7)) * 32) + ((lane >> 4) << 3);
    int nt   = tkt / ((m == 0 || m == 2) ? 4 : 8);
    int c    = nt * 16 + (lane & 15);

    union { uint4 q; unsigned short u[8]; } H, L;
    #pragma unroll
    for (int e = 0; e < 8; ++e) {
        int r = r0 + e;
        float v;
        if      (m == 0) v = W1[c * DIM  + r];
        else if (m == 1) v = W2[c * DIM2 + r];
        else if (m == 2) v = W2[r * DIM2 + c];
        else             v = W1[r * DIM  + c];
        unsigned short hb = f2bf(v);
        H.u[e] = hb;
        L.u[e] = f2bf(v - bf2f(hb));
    }
    size_t base = (size_t)m * 65536 + (size_t)(tkt * 64 + lane) * 8;
    *(uint4*)(pk + base) = H.q;
    if (m == 0) *(uint4*)(pk + base + 32768) = L.q;
}

// ---------------- fused main kernel ----------------
__global__ __launch_bounds__(NTHR, 1)
void fused_connection(const float* __restrict__ input_,
                      const float* __restrict__ b1,
                      const float* __restrict__ b2,
                      const unsigned short* __restrict__ pk,
                      float* __restrict__ out) {
    __shared__ __align__(16) float          vv [MB][132];   // v fp32
    __shared__ __align__(16) unsigned short xbH[MB][136];   // x hi plane (bf16 bits)
    __shared__ __align__(16) unsigned short xbL[MB][136];   // x lo plane
    __shared__ __align__(16) unsigned short vbH[MB][136];   // v hi plane
    __shared__ __align__(16) unsigned short aH [MB][264];   // a  bf16-hi
    __shared__ __align__(16) unsigned short mwH[MB][264];   // mw hi ; reused as mu hi
    __shared__ __align__(16) unsigned short vcH[MB][136];   // vc hi

    const int t    = threadIdx.x;
    const int lane = t & 63;
    const int w    = t >> 6;             // wave id 0..7
    const int b0   = blockIdx.x * MB;
    const int arow = lane & 15;          // A-frag row / C-frag col component
    const int kg   = (lane >> 4) << 3;   // k-offset of this lane group
    const int rbase = (lane >> 4) << 2;  // C/D row base (verified m89 layout)

    // ---- prefetch pass-1 B fragments (no dependencies; overlap with staging) ----
    uint4 b1hq[2][4], b1lq[2][4];
    #pragma unroll
    for (int nt2 = 0; nt2 < 2; ++nt2)
        #pragma unroll
        for (int kt = 0; kt < 4; ++kt) {
            const unsigned short* bp = pk + (size_t)((((w * 2 + nt2) * 4 + kt) * 64 + lane) * 8);
            b1hq[nt2][kt] = *(const uint4*)bp;
            b1lq[nt2][kt] = *(const uint4*)(bp + 32768);
        }

    // ---- phase 0: load x|v, convert in-register, stage planes; v -> out ----
    {
        int prow = t >> 5;               // 0..15
        int pc   = (t & 31) * 8;         // 0..248
        const float4* src = (const float4*)(input_ + (size_t)(b0 + prow) * DIM2 + pc);
        float4 f0 = src[0], f1 = src[1];
        float fa[8] = {f0.x, f0.y, f0.z, f0.w, f1.x, f1.y, f1.z, f1.w};
        if (pc < DIM) {
            union { unsigned short u[8]; uint4 q; } H, L;
            #pragma unroll
            for (int e = 0; e < 8; ++e) {
                unsigned short hb = f2bf(fa[e]);
                H.u[e] = hb;
                L.u[e] = f2bf(fa[e] - bf2f(hb));
            }
            *(uint4*)&xbH[prow][pc] = H.q;
            *(uint4*)&xbL[prow][pc] = L.q;
        } else {
            int c = pc - DIM;
            *(float4*)&vv[prow][c]     = f0;
            *(float4*)&vv[prow][c + 4] = f1;
            union { unsigned short u[8]; uint4 q; } H;
            #pragma unroll
            for (int e = 0; e < 8; ++e) H.u[e] = f2bf(fa[e]);
            *(uint4*)&vbH[prow][c] = H.q;
            // v -> out[:, :128] straight from registers
            float4* op = (float4*)(out + (size_t)(b0 + prow) * DIM2 + c);
            op[0] = f0; op[1] = f1;
        }
    }
    __syncthreads();

    // ---- Pass 1: B=W1T -> h = x.W1^T + b1 (3-term split), w = v.W1^T (hi) ----
    uint4 b2q[8];
    {
        // prefetch pass-2 B
        const unsigned short* p1 = pk + 65536;
        #pragma unroll
        for (int kt = 0; kt < 8; ++kt)
            b2q[kt] = *(const uint4*)(p1 + (size_t)((w * 8 + kt) * 64 + lane) * 8);

        bf16x8 xH[4], xL[4], vH[4];
        #pragma unroll
        for (int kt = 0; kt < 4; ++kt) {
            int k0 = kt * 32 + kg;
            xH[kt] = frag16(&xbH[arow][k0]);
            xL[kt] = frag16(&xbL[arow][k0]);
            vH[kt] = frag16(&vbH[arow][k0]);
        }
        #pragma unroll
        for (int nt2 = 0; nt2 < 2; ++nt2) {
            int nt = w * 2 + nt2;
            f32x4 ha = {0.f, 0.f, 0.f, 0.f};
            f32x4 wa = {0.f, 0.f, 0.f, 0.f};
            #pragma unroll
            for (int kt = 0; kt < 4; ++kt) {
                BU bh, bl;
                bh.q = b1hq[nt2][kt];
                bl.q = b1lq[nt2][kt];
                ha = MFMA(xH[kt], bh.b, ha);
                ha = MFMA(xH[kt], bl.b, ha);
                ha = MFMA(xL[kt], bh.b, ha);
                wa = MFMA(vH[kt], bh.b, wa);
            }
            int col  = nt * 16 + arow;
            float bias = b1[col];
            #pragma unroll
            for (int reg = 0; reg < 4; ++reg) {
                int row = rbase + reg;
                float hv = ha[reg] + bias;
                bool  mk = hv > 0.f;
                aH[row][col]  = f2bf(mk ? hv : 0.f);
                mwH[row][col] = f2bf(mk ? wa[reg] : 0.f);
            }
        }
    }
    __syncthreads();

    // ---- Pass 2: B=W2T(hi) -> z = a.W2^T + b2 (-> s), t2 = mw.W2^T ; write vc ----
    float sreg[4];
    f32x4 t2a = {0.f, 0.f, 0.f, 0.f};
    uint4 b3q[2][4];
    {
        // prefetch pass-3 B
        const unsigned short* p2 = pk + 2 * 65536;
        #pragma unroll
        for (int nt2 = 0; nt2 < 2; ++nt2)
            #pragma unroll
            for (int kt = 0; kt < 4; ++kt)
                b3q[nt2][kt] = *(const uint4*)(p2 + (size_t)((((w * 2 + nt2) * 4 + kt) * 64 + lane) * 8));

        f32x4 za = {0.f, 0.f, 0.f, 0.f};
        #pragma unroll
        for (int kt = 0; kt < 8; ++kt) {
            int k0 = kt * 32 + kg;
            bf16x8 af = frag16(&aH[arow][k0]);
            bf16x8 mf = frag16(&mwH[arow][k0]);
            BU bh; bh.q = b2q[kt];
            za  = MFMA(af, bh.b, za);
            t2a = MFMA(mf, bh.b, t2a);
        }
        int   ci   = w * 16 + arow;            // i in [0,128)
        float sg_i = (ci < NSIGN) ? -1.f : 1.f;
        float b2v  = b2[ci];
        #pragma unroll
        for (int reg = 0; reg < 4; ++reg) {
            int row = rbase + reg;
            float z = za[reg] + b2v;
            float s = 1.f / (1.f + __expf(-z));
            sreg[reg] = s;
            float vvl = vv[row][ci];
            vcH[row][ci] = f2bf(vvl * vvl * sg_i * s * (1.f - s));
        }
    }
    __syncthreads();

    // ---- Pass 3: B=W2(hi) -> u = vc.W2 ; write mu = mask*u into mwH ----
    uint4 b4q[8];
    {
        // prefetch pass-4 B
        const unsigned short* p3 = pk + 3 * 65536;
        #pragma unroll
        for (int kt = 0; kt < 8; ++kt)
            b4q[kt] = *(const uint4*)(p3 + (size_t)((w * 8 + kt) * 64 + lane) * 8);

        bf16x8 cH[4];
        #pragma unroll
        for (int kt = 0; kt < 4; ++kt)
            cH[kt] = frag16(&vcH[arow][kt * 32 + kg]);
        #pragma unroll
        for (int nt2 = 0; nt2 < 2; ++nt2) {
            int nt = w * 2 + nt2;
            f32x4 ua = {0.f, 0.f, 0.f, 0.f};
            #pragma unroll
            for (int kt = 0; kt < 4; ++kt) {
                BU bh; bh.q = b3q[nt2][kt];
                ua = MFMA(cH[kt], bh.b, ua);
            }
            int ck = nt * 16 + arow;           // k in [0,256)
            #pragma unroll
            for (int reg = 0; reg < 4; ++reg) {
                int row = rbase + reg;
                bool mk = aH[row][ck] != 0;    // a>0 <=> stored bf16 nonzero
                mwH[row][ck] = f2bf(mk ? ua[reg] : 0.f);
            }
        }
    }
    __syncthreads();

    // ---- Pass 4: B=W1(hi) -> t1 = mu.W1 ; epilogue dv ----
    {
        f32x4 t1a = {0.f, 0.f, 0.f, 0.f};
        #pragma unroll
        for (int kt = 0; kt < 8; ++kt) {
            bf16x8 mf = frag16(&mwH[arow][kt * 32 + kg]);
            BU bh; bh.q = b4q[kt];
            t1a = MFMA(mf, bh.b, t1a);
        }
        int   cj   = w * 16 + arow;            // same col as pass 2 -> sreg/t2a align
        float sg_j = (cj < NSIGN) ? -1.f : 1.f;
        #pragma unroll
        for (int reg = 0; reg < 4; ++reg) {
            int row = rbase + reg;
            float s  = sreg[reg];
            float cv = sg_j * s * (1.f - s);
            float gi = 1.f / (sg_j * (s + CCONST));
            float vvl = vv[row][cj];
            float dv = fmaf(-gi, t1a[reg], 2.f * vvl * gi * cv * t2a[reg]);
            out[(size_t)(b0 + row) * DIM2 + DIM + cj] = dv;
        }
    }
}

extern "C" void kernel_launch(void* const* d_in, const int* in_sizes, int n_in,
                              void* d_out, int out_size, void* d_ws, size_t ws_size,
                              hipStream_t stream) {
    // inputs: t, input_, W1, b1, W2, b2
    const float* input_ = (const float*)d_in[1];
    const float* W1 = (const float*)d_in[2];
    const float* b1 = (const float*)d_in[3];
    const float* W2 = (const float*)d_in[4];
    const float* b2 = (const float*)d_in[5];
    float* out = (float*)d_out;
    unsigned short* pk = (unsigned short*)d_ws;   // 4 packs x 128 KB = 512 KB

    const int batch = in_sizes[1] / DIM2;

    prep_pack<<<64, 256, 0, stream>>>(W1, W2, pk);
    fused_connection<<<batch / MB, NTHR, 0, stream>>>(input_, b1, b2, pk, out);
}